// Round 1
// baseline (12024.661 us; speedup 1.0000x reference)
//
#include <hip/hip_runtime.h>
#include <hip/hip_bf16.h>
#include <math.h>

// Problem dims
#define B_  48
#define T_  200
#define C_  53
#define E_  32
#define H_  64
#define C2_ 2809
#define E1_ 140
#define E2_ 1404
#define TS  56          // padded LDS row stride (floats) for 53-wide tiles

typedef long long i64;

struct __align__(16) F4 { float v[4]; };

__device__ __forceinline__ float wredsum(float v){
  #pragma unroll
  for (int o = 32; o > 0; o >>= 1) v += __shfl_xor(v, o);
  return v;
}
__device__ __forceinline__ float sigm(float x){ return 1.f/(1.f + __expf(-x)); }
__device__ __forceinline__ float tanhx(float x){
  float a = fabsf(x);
  float e = __expf(-2.f*a);
  float t = (1.f - e)/(1.f + e);
  return copysignf(t, x);
}

// ---------------- ws layout (float offsets) ----------------
#define OFF_SIGMA 0
#define OFF_M     200
#define OFF_WHHT  9800
#define OFF_WQKVT 22088
#define OFF_P     34376
#define OFF_R0    34568
#define OFF_MM    34760
#define OFF_M2    38856
#define OFF_M4    42952
#define OFF_M5    47048
#define OFF_AMEAN 51144
#define OFF_E     185976
#define OFF_CA    1529976
#define OFF_CB    1530116
#define OFF_APRE  1530256
#define OFF_A     1539856
#define OFF_G2T   1549456
// total ~1,746,016 floats = ~7 MB

// ---------------- prep: transposes + p/r0 ----------------
__global__ void k_prep1(const float* __restrict__ w_hh, const float* __restrict__ wq,
                        const float* __restrict__ wk, const float* __restrict__ wv,
                        const float* __restrict__ w_ih, const float* __restrict__ emb_w,
                        const float* __restrict__ emb_b, const float* __restrict__ b_ih,
                        const float* __restrict__ w_g2,
                        float* whhT, float* wqkvT, float* g2t, float* p, float* r0){
  int idx0 = blockIdx.x*blockDim.x + threadIdx.x;
  int stride = gridDim.x*blockDim.x;
  for (int i = idx0; i < 64*192; i += stride){ int kk = i/192, g = i%192; whhT[i] = w_hh[g*64+kk]; }
  for (int i = idx0; i < 64*192; i += stride){
    int kk = i/192, a = i%192;
    float v = (a < 64) ? wq[a*64+kk] : (a < 128) ? wk[(a-64)*64+kk] : wv[(a-128)*64+kk];
    wqkvT[i] = v;
  }
  for (int i = idx0; i < 140*1404; i += stride){ int k = i/1404, n = i%1404; g2t[i] = w_g2[n*140+k]; }
  for (int i = idx0; i < 192; i += stride){
    float s1 = 0.f, s2 = 0.f;
    for (int e = 0; e < 32; e++){ float w = w_ih[i*32+e]; s1 += w*emb_w[e]; s2 += w*emb_b[e]; }
    p[i] = s1; r0[i] = s2 + b_ih[i];
  }
}

// ---------------- prep: M powers + sigma[t] (serial power iteration) ----------------
// ref does 5x {v=norm(Wt u); u=norm(W v)}; sigma=u.(Wv). With M=W Wt this is:
//   z = M^4 u_prev ; sigma = ||M z|| / sqrt(z.M z) ; u = norm(M^5 u_prev)
__global__ void k_prep2(const float* __restrict__ wv, const float* __restrict__ u0,
                        float* Wm, float* Wm2, float* Wm4, float* Wm5, float* sigma){
  int r = threadIdx.x; // 64 threads, one wave
  for (int c = 0; c < 64; c++){
    float s = 0.f;
    for (int k = 0; k < 64; k++) s += wv[r*64+k]*wv[c*64+k];
    Wm[r*64+c] = s;
  }
  __syncthreads();
  for (int c = 0; c < 64; c++){
    float s = 0.f;
    for (int k = 0; k < 64; k++) s += Wm[r*64+k]*Wm[k*64+c];
    Wm2[r*64+c] = s;
  }
  __syncthreads();
  for (int c = 0; c < 64; c++){
    float s = 0.f;
    for (int k = 0; k < 64; k++) s += Wm2[r*64+k]*Wm2[k*64+c];
    Wm4[r*64+c] = s;
  }
  __syncthreads();
  for (int c = 0; c < 64; c++){
    float s = 0.f;
    for (int k = 0; k < 64; k++) s += Wm4[r*64+k]*Wm[k*64+c];
    Wm5[r*64+c] = s;
  }
  __syncthreads();
  __shared__ float su[64];
  su[r] = u0[r];
  __syncthreads();
  for (int t = 0; t < T_; t++){
    float z = 0.f, w = 0.f;
    for (int k = 0; k < 64; k++){ float uk = su[k]; z += Wm4[r*64+k]*uk; w += Wm5[r*64+k]*uk; }
    float nw = wredsum(w*w);
    float zw = wredsum(z*w);
    float sg = sqrtf(nw / fmaxf(zw, 1e-35f));
    if (r == 0) sigma[t] = sg;
    float wn = w * (1.f/sqrtf(fmaxf(nw, 1e-35f)));
    __syncthreads();
    su[r] = wn;
    __syncthreads();
  }
}

// ---------------- the scan: one WG per batch, all 200 steps on-chip ----------------
__global__ __launch_bounds__(512) void k_scan(
    const float* __restrict__ x, const float* __restrict__ b_hh,
    const float* __restrict__ bq, const float* __restrict__ bk, const float* __restrict__ bv,
    const float* __restrict__ whhT, const float* __restrict__ wqkvT,
    const float* __restrict__ wp, const float* __restrict__ wr0,
    const float* __restrict__ sigma, float* __restrict__ wm, float* __restrict__ outAL){
  __shared__ __align__(16) float L[15040];
  float* R1 = L;            // [64][56] hT -> hg (in place) -> eigen Y -> h'
  float* R2 = L + 3584;     // [53][64] val -> eigen Ytr [53][56]
  float* R3 = L + 6976;     // [64][56] qT -> S [53][56] -> eigen ping
  float* R4 = L + 10560;    // [64][56] kT -> St -> eigen ping
  float* Lp  = L + 14144;   // p[192]
  float* Lr0 = Lp + 192;
  float* Lbh = Lr0 + 192;   // b_hh
  float* Lb3 = Lbh + 192;   // bq|bk|bv
  float* Lsc = Lb3 + 192;   // 48 scalars: [0]=ssq0, per iter j: [3j-2]=ssq,[3j-1]=tr2,[3j]=tr1
  int tid = threadIdx.x;
  int b = blockIdx.x;

  for (int i = tid; i < 192; i += 512){
    Lp[i] = wp[i]; Lr0[i] = wr0[i]; Lbh[i] = b_hh[i];
    Lb3[i] = (i < 64) ? bq[i] : (i < 128) ? bk[i-64] : bv[i-128];
  }
  for (int i = tid; i < 3584; i += 512) R1[i] = 0.f;  // h0 = 0 (+ zero pads)
  __syncthreads();

  int ct4 = tid >> 4, jt4 = tid & 15;   // 224-thread tilings (4x4)
  int c0g = ct4*4, j0g = jt4*4;
  int it14 = tid/14, jt14 = tid%14;     // 196-thread scores tiling
  int i0s = it14*4, j0s = jt14*4;

  for (int t = 0; t < T_; t++){
    // ---- GH: gh = h @ w_hh^T (+b_hh), 3 gates fused per thread ----
    if (tid < 48) Lsc[tid] = 0.f;
    float gacc[3][4][4];
    if (tid < 224){
      #pragma unroll
      for (int g = 0; g < 3; g++)
        #pragma unroll
        for (int ji = 0; ji < 4; ji++){
          float bb = Lbh[g*64 + j0g + ji];
          #pragma unroll
          for (int ci = 0; ci < 4; ci++) gacc[g][ji][ci] = bb;
        }
      for (int kk = 0; kk < 64; kk++){
        F4 hv = *(F4*)&R1[kk*TS + c0g];
        F4 w0 = *(const F4*)&whhT[kk*192 + j0g];
        F4 w1 = *(const F4*)&whhT[kk*192 + 64 + j0g];
        F4 w2 = *(const F4*)&whhT[kk*192 + 128 + j0g];
        #pragma unroll
        for (int ji = 0; ji < 4; ji++)
          #pragma unroll
          for (int ci = 0; ci < 4; ci++){
            gacc[0][ji][ci] += hv.v[ci]*w0.v[ji];
            gacc[1][ji][ci] += hv.v[ci]*w1.v[ji];
            gacc[2][ji][ci] += hv.v[ci]*w2.v[ji];
          }
      }
    }
    __syncthreads();
    // ---- GATES: hg written in place over hT (same cells) ----
    if (tid < 224){
      float xv[4];
      #pragma unroll
      for (int ci = 0; ci < 4; ci++){
        int c = c0g + ci;
        xv[ci] = (c < C_) ? x[(i64)(b*T_ + t)*C_ + c] : 0.f;
      }
      F4 p0 = *(F4*)&Lp[j0g], p1 = *(F4*)&Lp[64+j0g], p2 = *(F4*)&Lp[128+j0g];
      F4 q0 = *(F4*)&Lr0[j0g], q1 = *(F4*)&Lr0[64+j0g], q2 = *(F4*)&Lr0[128+j0g];
      #pragma unroll
      for (int ji = 0; ji < 4; ji++){
        F4 hold = *(F4*)&R1[(j0g+ji)*TS + c0g];
        F4 o;
        #pragma unroll
        for (int ci = 0; ci < 4; ci++){
          float rr = sigm(xv[ci]*p0.v[ji] + q0.v[ji] + gacc[0][ji][ci]);
          float zz = sigm(xv[ci]*p1.v[ji] + q1.v[ji] + gacc[1][ji][ci]);
          float nn = tanhx(xv[ci]*p2.v[ji] + q2.v[ji] + rr*gacc[2][ji][ci]);
          float hg = (1.f - zz)*nn + zz*hold.v[ci];
          o.v[ci] = (c0g + ci < C_) ? hg : 0.f;
        }
        *(F4*)&R1[(j0g+ji)*TS + c0g] = o;
      }
    }
    __syncthreads();
    // ---- QKV: q->R3 (qT), k->R4 (kT), val->R2 (row-major) ----
    if (tid < 336){
      int ct = tid/48, gt = tid%48;
      int c0 = ct*8, g0 = gt*4;
      float qacc[4][8];
      #pragma unroll
      for (int gi = 0; gi < 4; gi++)
        #pragma unroll
        for (int ci = 0; ci < 8; ci++) qacc[gi][ci] = 0.f;
      for (int kk = 0; kk < 64; kk++){
        F4 a0 = *(F4*)&R1[kk*TS + c0];
        F4 a1 = *(F4*)&R1[kk*TS + c0 + 4];
        F4 w = *(const F4*)&wqkvT[kk*192 + g0];
        #pragma unroll
        for (int gi = 0; gi < 4; gi++)
          #pragma unroll
          for (int ci = 0; ci < 4; ci++){
            qacc[gi][ci]   += a0.v[ci]*w.v[gi];
            qacc[gi][ci+4] += a1.v[ci]*w.v[gi];
          }
      }
      if (g0 < 128){
        float* dst = (g0 < 64) ? R3 : R4;
        int gb = g0 & 63;
        #pragma unroll
        for (int gi = 0; gi < 4; gi++){
          float bias = Lb3[g0 + gi];
          F4 lo, hi;
          #pragma unroll
          for (int ci = 0; ci < 4; ci++){
            lo.v[ci] = (c0+ci   < C_) ? qacc[gi][ci]   + bias : 0.f;
            hi.v[ci] = (c0+ci+4 < C_) ? qacc[gi][ci+4] + bias : 0.f;
          }
          *(F4*)&dst[(gb+gi)*TS + c0] = lo;
          *(F4*)&dst[(gb+gi)*TS + c0 + 4] = hi;
        }
      } else {
        float invs = 1.f/sigma[t];
        int a0i = g0 - 128;
        #pragma unroll
        for (int ci = 0; ci < 8; ci++){
          int c = c0 + ci;
          if (c < C_){
            F4 o;
            #pragma unroll
            for (int gi = 0; gi < 4; gi++) o.v[gi] = qacc[gi][ci]*invs + Lb3[128 + a0i + gi];
            *(F4*)&R2[c*64 + a0i] = o;
          }
        }
      }
    }
    __syncthreads();
    // ---- SCORES (to regs) + raw align write + ||S||_F^2 ----
    float sacc[4][4];
    if (tid < 196){
      #pragma unroll
      for (int ii = 0; ii < 4; ii++)
        #pragma unroll
        for (int jj = 0; jj < 4; jj++) sacc[ii][jj] = 0.f;
      for (int kk = 0; kk < 64; kk++){
        F4 qa = *(F4*)&R3[kk*TS + i0s];
        F4 kb = *(F4*)&R4[kk*TS + j0s];
        #pragma unroll
        for (int ii = 0; ii < 4; ii++)
          #pragma unroll
          for (int jj = 0; jj < 4; jj++) sacc[ii][jj] += qa.v[ii]*kb.v[jj];
      }
      float* ALrow = outAL + (i64)(b*T_ + t)*C2_;
      #pragma unroll
      for (int ii = 0; ii < 4; ii++){
        int i = i0s + ii;
        if (i < C_){
          #pragma unroll
          for (int jj = 0; jj < 4; jj++){
            int j = j0s + jj;
            if (j < C_) ALrow[i*C_ + j] = sacc[ii][jj];
          }
        }
      }
    }
    {
      float ssq = 0.f;
      if (tid < 196){
        #pragma unroll
        for (int ii = 0; ii < 4; ii++)
          #pragma unroll
          for (int jj = 0; jj < 4; jj++) ssq += sacc[ii][jj]*sacc[ii][jj];
      }
      ssq = wredsum(ssq);
      if ((tid & 63) == 0 && ssq != 0.f) atomicAdd(&Lsc[0], ssq);
    }
    __syncthreads();
    // ---- S/St into R3/R4 (qT/kT dead) ----
    if (tid < 196){
      #pragma unroll
      for (int ii = 0; ii < 4; ii++){
        int i = i0s + ii;
        if (i < C_){
          F4 o;
          #pragma unroll
          for (int jj = 0; jj < 4; jj++) o.v[jj] = sacc[ii][jj];
          *(F4*)&R3[i*TS + j0s] = o;
        }
      }
      #pragma unroll
      for (int jj = 0; jj < 4; jj++){
        int j = j0s + jj;
        if (j < C_){
          #pragma unroll
          for (int ii = 0; ii < 4; ii++) R4[j*TS + i0s + ii] = sacc[ii][jj]; // writes i-pads with 0
        }
      }
    }
    __syncthreads();
    // ---- h_raw = S @ val  (held in regs; S gets destroyed by squaring) ----
    float hraw[4][4];
    if (tid < 224){
      #pragma unroll
      for (int ii = 0; ii < 4; ii++)
        #pragma unroll
        for (int jj = 0; jj < 4; jj++) hraw[ii][jj] = 0.f;
      for (int kk = 0; kk < C_; kk++){
        F4 sa = *(F4*)&R4[kk*TS + c0g];     // St[c][i] = S[i][c]
        F4 vb = *(F4*)&R2[kk*64 + j0g];
        #pragma unroll
        for (int ii = 0; ii < 4; ii++)
          #pragma unroll
          for (int jj = 0; jj < 4; jj++) hraw[ii][jj] += sa.v[ii]*vb.v[jj];
      }
    }
    __syncthreads();
    // ---- EIGEN: Gelfand squaring chain + trace-quadratic tail ----
    float* Xrm = R3; float* Xtr = R4; float* Yrm = R1; float* Ytr = R2;
    float sprev = fmaxf(Lsc[0], 1e-35f);
    float Gacc = 0.f, prevest = 1e30f, est = 0.f;
    int cnt = 0;
    for (int j = 1; j <= 12; j++){
      float inv = 1.f/sprev;
      if (tid < 98){
        int rt = tid/7, ctt = tid%7;
        int r0 = rt*4, c0 = ctt*8;
        float ea[4][8];
        #pragma unroll
        for (int ri = 0; ri < 4; ri++)
          #pragma unroll
          for (int ci = 0; ci < 8; ci++) ea[ri][ci] = 0.f;
        for (int k = 0; k < C_; k++){
          F4 av = *(F4*)&Xtr[k*TS + r0];
          F4 b0 = *(F4*)&Xrm[k*TS + c0];
          F4 b1 = *(F4*)&Xrm[k*TS + c0 + 4];
          #pragma unroll
          for (int ri = 0; ri < 4; ri++){
            #pragma unroll
            for (int ci = 0; ci < 4; ci++){
              ea[ri][ci]   += av.v[ri]*b0.v[ci];
              ea[ri][ci+4] += av.v[ri]*b1.v[ci];
            }
          }
        }
        #pragma unroll
        for (int ri = 0; ri < 4; ri++){
          int r = r0 + ri;
          if (r < C_){
            F4 lo, hi;
            #pragma unroll
            for (int ci = 0; ci < 4; ci++){
              lo.v[ci] = (c0+ci   < C_) ? ea[ri][ci]*inv   : 0.f;
              hi.v[ci] = (c0+ci+4 < C_) ? ea[ri][ci+4]*inv : 0.f;
            }
            *(F4*)&Yrm[r*TS + c0] = lo;
            *(F4*)&Yrm[r*TS + c0 + 4] = hi;
            #pragma unroll
            for (int ci = 0; ci < 8; ci++){
              int c = c0 + ci;
              if (c < C_) Ytr[c*TS + r] = (ci < 4) ? lo.v[ci] : hi.v[ci-4];
            }
          } else {
            #pragma unroll
            for (int ci = 0; ci < 8; ci++){
              int c = c0 + ci;
              if (c < C_) Ytr[c*TS + r] = 0.f;  // zero tr pad cols
            }
          }
        }
      }
      __syncthreads();
      float ssq = 0.f, tr2 = 0.f, tr1 = 0.f;
      for (int s = tid; s < 742; s += 512){     // 53 rows x 14 quads
        int r = s/14, q = (s - r*14)*4;
        F4 y  = *(F4*)&Yrm[r*TS + q];
        F4 yt = *(F4*)&Ytr[r*TS + q];
        #pragma unroll
        for (int u = 0; u < 4; u++){ ssq += y.v[u]*y.v[u]; tr2 += y.v[u]*yt.v[u]; }
      }
      if (tid < C_) tr1 = Yrm[tid*TS + tid];
      ssq = wredsum(ssq); tr2 = wredsum(tr2); tr1 = wredsum(tr1);
      if ((tid & 63) == 0){
        atomicAdd(&Lsc[3*j-2], ssq);
        atomicAdd(&Lsc[3*j-1], tr2);
        atomicAdd(&Lsc[3*j],   tr1);
      }
      __syncthreads();
      float s2  = fmaxf(Lsc[3*j-2], 1e-35f);
      float T2v = Lsc[3*j-1];
      float T1v = Lsc[3*j];
      float tj = sqrtf(s2);
      Gacc += ldexpf(0.5f*log2f(s2), -j);
      float t1n = T1v/tj;
      float t2n = T2v/s2;
      float dq   = 0.5f*(t1n*t1n - t2n);
      float disc = 2.f*t2n - t1n*t1n;
      float rq = (disc >= 0.f) ? 0.5f*(fabsf(t1n) + sqrtf(disc)) : sqrtf(fmaxf(dq, 1e-30f));
      rq = fminf(fmaxf(rq, 0.02f), 1.5f);
      est = Gacc + ldexpf(log2f(rq), -j);
      if (fabsf(est - prevest) < 1e-4f) cnt++; else cnt = 0;
      prevest = est;
      sprev = s2;
      { float* tp = Xrm; Xrm = Yrm; Yrm = tp; tp = Xtr; Xtr = Ytr; Ytr = tp; }
      if (j >= 5 && cnt >= 2) break;
    }
    float s0 = fmaxf(Lsc[0], 1e-35f);
    float mval = sqrtf(s0)*exp2f(est);
    float invm = 1.f/mval;
    if (tid == 0) wm[b*T_ + t] = mval;
    // ---- h' = h_raw/m into R1 (hT layout) ----
    if (tid < 224){
      #pragma unroll
      for (int jj = 0; jj < 4; jj++){
        F4 o;
        #pragma unroll
        for (int ii = 0; ii < 4; ii++) o.v[ii] = (c0g + ii < C_) ? hraw[ii][jj]*invm : 0.f;
        *(F4*)&R1[(j0g+jj)*TS + c0g] = o;
      }
    }
    __syncthreads();
  }
}

// ---------------- align /= m, fused with T-mean ----------------
__global__ void k_scalemean(float* __restrict__ AL, const float* __restrict__ m,
                            float* __restrict__ amean){
  int b = blockIdx.x/11, ch = blockIdx.x%11;
  int c2 = ch*256 + threadIdx.x;
  if (c2 >= C2_) return;
  float acc = 0.f;
  for (int t = 0; t < T_; t++){
    float im = 1.f/m[b*T_ + t];
    i64 idx = (i64)(b*T_ + t)*C2_ + c2;
    float v = AL[idx]*im;
    AL[idx] = v;
    acc += v;
  }
  amean[(i64)b*C2_ + c2] = acc*(1.f/(float)T_);
}

// ---------------- e = (align * mean) @ w_g1^T  (K-split x4, atomics) ----------------
__global__ __launch_bounds__(128) void k_gemm1(const float* __restrict__ AL,
                                               const float* __restrict__ amean,
                                               const float* __restrict__ w_g1,
                                               float* __restrict__ e){
  __shared__ __align__(16) float At[64][68];
  __shared__ __align__(16) float Bt[64][148];
  int mt = blockIdx.x >> 2, ks = blockIdx.x & 3;
  int tid = threadIdx.x;
  float acc[8][12];
  #pragma unroll
  for (int ri = 0; ri < 8; ri++)
    #pragma unroll
    for (int ci = 0; ci < 12; ci++) acc[ri][ci] = 0.f;
  int rg = tid/12, cg = tid%12;
  int r0 = rg*8, cc0 = cg*12;
  for (int kb = 0; kb < 11; kb++){
    int k0 = (ks*11 + kb)*64;
    for (int idx = tid; idx < 4096; idx += 128){
      int r = idx >> 6, i = idx & 63;
      int kk = k0 + i;
      int row = mt*64 + r, bb = row/T_;
      float v = 0.f;
      if (kk < C2_) v = AL[(i64)row*C2_ + kk]*amean[(i64)bb*C2_ + kk];
      At[i][r] = v;
    }
    for (int idx = tid; idx < 9216; idx += 128){
      int c = idx >> 6, i = idx & 63;
      int kk = k0 + i;
      float v = 0.f;
      if (c < E1_ && kk < C2_) v = w_g1[(i64)c*C2_ + kk];
      Bt[i][c] = v;
    }
    __syncthreads();
    if (tid < 96){
      for (int i = 0; i < 64; i++){
        F4 a0 = *(F4*)&At[i][r0]; F4 a1 = *(F4*)&At[i][r0+4];
        F4 b0 = *(F4*)&Bt[i][cc0]; F4 b1 = *(F4*)&Bt[i][cc0+4]; F4 b2 = *(F4*)&Bt[i][cc0+8];
        #pragma unroll
        for (int ri = 0; ri < 8; ri++){
          float av = (ri < 4) ? a0.v[ri] : a1.v[ri-4];
          #pragma unroll
          for (int ci = 0; ci < 12; ci++){
            float bv = (ci < 4) ? b0.v[ci] : (ci < 8) ? b1.v[ci-4] : b2.v[ci-8];
            acc[ri][ci] += av*bv;
          }
        }
      }
    }
    __syncthreads();
  }
  if (tid < 96){
    #pragma unroll
    for (int ri = 0; ri < 8; ri++)
      #pragma unroll
      for (int ci = 0; ci < 12; ci++){
        int c = cc0 + ci;
        if (c < E1_) atomicAdd(&e[(i64)(mt*64 + r0 + ri)*E1_ + c], acc[ri][ci]);
      }
  }
}

// ---------------- BN stats -> coefA/coefB (b_g1 absorbed by BN) ----------------
__global__ void k_bnstats(const float* __restrict__ e, const float* __restrict__ bn_g,
                          const float* __restrict__ bn_b, float* cA, float* cB){
  __shared__ float s1a[256], s2a[256];
  int c = blockIdx.x, tid = threadIdx.x;
  float s1 = 0.f, s2 = 0.f;
  for (int row = tid; row < B_*T_; row += 256){
    float v = e[(i64)row*E1_ + c];
    s1 += v; s2 += v*v;
  }
  s1a[tid] = s1; s2a[tid] = s2; __syncthreads();
  for (int s = 128; s > 0; s >>= 1){
    if (tid < s){ s1a[tid] += s1a[tid+s]; s2a[tid] += s2a[tid+s]; }
    __syncthreads();
  }
  if (tid == 0){
    float n = (float)(B_*T_);
    float mu = s1a[0]/n;
    float var = s2a[0]/n - mu*mu;
    float a = bn_g[c]/sqrtf(var + 1e-5f);
    cA[c] = a; cB[c] = bn_b[c] - mu*a;
  }
}

// ---------------- a_pre = relu(BN(e)) @ w_g2^T -> relu(+b_g2) . w_g3 (fused, atomics) ---
__global__ __launch_bounds__(128) void k_gemm2(const float* __restrict__ e,
                                               const float* __restrict__ cA, const float* __restrict__ cB,
                                               const float* __restrict__ g2t,
                                               const float* __restrict__ b_g2, const float* __restrict__ w_g3,
                                               float* __restrict__ apre){
  __shared__ __align__(16) float At2[140][68];
  int mt = blockIdx.x/30, nc = blockIdx.x%30;
  int tid = threadIdx.x;
  int nbase = nc*48;
  for (int idx = tid; idx < 64*140; idx += 128){
    int r = idx/140, k = idx - r*140;
    float v = e[(i64)(mt*64 + r)*E1_ + k]*cA[k] + cB[k];
    At2[k][r] = fmaxf(v, 0.f);
  }
  __syncthreads();
  if (tid < 96){
    int rg = tid/6, ng = tid%6;
    int r0 = rg*4, n0 = nbase + ng*8;
    float acc[4][8];
    #pragma unroll
    for (int ri = 0; ri < 4; ri++)
      #pragma unroll
      for (int ni = 0; ni < 8; ni++) acc[ri][ni] = 0.f;
    for (int k = 0; k < E1_; k++){
      F4 a = *(F4*)&At2[k][r0];
      float bvv[8];
      if (n0 + 8 <= E2_){
        F4 b0 = *(const F4*)&g2t[(i64)k*E2_ + n0];
        F4 b1 = *(const F4*)&g2t[(i64)k*E2_ + n0 + 4];
        #pragma unroll
        for (int u = 0; u < 4; u++){ bvv[u] = b0.v[u]; bvv[u+4] = b1.v[u]; }
      } else {
        #pragma unroll
        for (int ni = 0; ni < 8; ni++){ int n = n0+ni; bvv[ni] = (n < E2_) ? g2t[(i64)k*E2_ + n] : 0.f; }
      }
      #pragma unroll
      for (int ri = 0; ri < 4; ri++)
        #pragma unroll
        for (int ni = 0; ni < 8; ni++) acc[ri][ni] += a.v[ri]*bvv[ni];
    }
    #pragma unroll
    for (int ri = 0; ri < 4; ri++){
      float s = 0.f;
      #pragma unroll
      for (int ni = 0; ni < 8; ni++){
        int n = n0 + ni;
        if (n < E2_){
          float a2 = acc[ri][ni] + b_g2[n];
          if (a2 > 0.f) s += a2*w_g3[n];
        }
      }
      atomicAdd(&apre[mt*64 + r0 + ri], s);
    }
  }
}

// ---------------- softmax over T (b_g3 absorbed) + logits init ----------------
__global__ void k_soft(const float* __restrict__ apre, const float* __restrict__ b_clf,
                       float* __restrict__ wa, float* __restrict__ out){
  __shared__ float sr[256];
  int b = blockIdx.x, tid = threadIdx.x;
  float v = (tid < T_) ? apre[b*T_ + tid] : -3.4e38f;
  sr[tid] = v; __syncthreads();
  for (int s = 128; s > 0; s >>= 1){ if (tid < s) sr[tid] = fmaxf(sr[tid], sr[tid+s]); __syncthreads(); }
  float mx = sr[0]; __syncthreads();
  float ev = (tid < T_) ? __expf(v - mx) : 0.f;
  sr[tid] = ev; __syncthreads();
  for (int s = 128; s > 0; s >>= 1){ if (tid < s) sr[tid] += sr[tid+s]; __syncthreads(); }
  float den = sr[0];
  if (tid < T_) wa[b*T_ + tid] = ev/den;
  if (b == 0 && tid < 2*B_) out[tid] = b_clf[tid & 1];
}

// ---------------- dnc = sum_t align*a ; logits += dnc @ w_clf^T ----------------
__global__ void k_dnc(const float* __restrict__ AL, const float* __restrict__ wa,
                      const float* __restrict__ w_clf, float* __restrict__ out){
  int b = blockIdx.x/11, ch = blockIdx.x%11;
  int c2 = ch*256 + threadIdx.x;
  float acc = 0.f;
  if (c2 < C2_){
    for (int t = 0; t < T_; t++)
      acc += AL[(i64)(b*T_ + t)*C2_ + c2]*wa[b*T_ + t];
    out[96 + (i64)b*C2_ + c2] = acc;
  }
  float p0 = (c2 < C2_) ? acc*w_clf[c2]        : 0.f;
  float p1 = (c2 < C2_) ? acc*w_clf[C2_ + c2]  : 0.f;
  p0 = wredsum(p0); p1 = wredsum(p1);
  if ((threadIdx.x & 63) == 0){
    atomicAdd(&out[b*2 + 0], p0);
    atomicAdd(&out[b*2 + 1], p1);
  }
}

extern "C" void kernel_launch(void* const* d_in, const int* in_sizes, int n_in,
                              void* d_out, int out_size, void* d_ws, size_t ws_size,
                              hipStream_t stream){
  const float* x     = (const float*)d_in[0];
  const float* emb_w = (const float*)d_in[1];
  const float* emb_b = (const float*)d_in[2];
  const float* w_ih  = (const float*)d_in[3];
  const float* w_hh  = (const float*)d_in[4];
  const float* b_ih  = (const float*)d_in[5];
  const float* b_hh  = (const float*)d_in[6];
  const float* wq    = (const float*)d_in[7];
  const float* bq    = (const float*)d_in[8];
  const float* wk    = (const float*)d_in[9];
  const float* bk    = (const float*)d_in[10];
  const float* wv_in = (const float*)d_in[11];
  const float* bv    = (const float*)d_in[12];
  const float* u0    = (const float*)d_in[13];
  const float* w_g1  = (const float*)d_in[14];
  const float* bn_g  = (const float*)d_in[16];
  const float* bn_b  = (const float*)d_in[17];
  const float* w_g2  = (const float*)d_in[18];
  const float* b_g2  = (const float*)d_in[19];
  const float* w_g3  = (const float*)d_in[20];
  const float* w_clf = (const float*)d_in[22];
  const float* b_clf = (const float*)d_in[23];
  float* out = (float*)d_out;
  float* W = (float*)d_ws;

  float* wsig   = W + OFF_SIGMA;
  float* wm     = W + OFF_M;
  float* whhT   = W + OFF_WHHT;
  float* wqkvT  = W + OFF_WQKVT;
  float* wp     = W + OFF_P;
  float* wr0    = W + OFF_R0;
  float* wM     = W + OFF_MM;
  float* wM2    = W + OFF_M2;
  float* wM4    = W + OFF_M4;
  float* wM5    = W + OFF_M5;
  float* wamean = W + OFF_AMEAN;
  float* we     = W + OFF_E;
  float* wcA    = W + OFF_CA;
  float* wcB    = W + OFF_CB;
  float* wapre  = W + OFF_APRE;
  float* wa     = W + OFF_A;
  float* wg2t   = W + OFF_G2T;

  float* outAL = out + 96 + (i64)B_*C2_;  // align region

  hipMemsetAsync(we, 0, (size_t)(B_*T_)*E1_*sizeof(float), stream);
  hipMemsetAsync(wapre, 0, (size_t)(B_*T_)*sizeof(float), stream);

  k_prep1<<<96, 256, 0, stream>>>(w_hh, wq, wk, wv_in, w_ih, emb_w, emb_b, b_ih, w_g2,
                                  whhT, wqkvT, wg2t, wp, wr0);
  k_prep2<<<1, 64, 0, stream>>>(wv_in, u0, wM, wM2, wM4, wM5, wsig);
  k_scan<<<B_, 512, 0, stream>>>(x, b_hh, bq, bk, bv, whhT, wqkvT, wp, wr0, wsig, wm, outAL);
  k_scalemean<<<B_*11, 256, 0, stream>>>(outAL, wm, wamean);
  k_gemm1<<<600, 128, 0, stream>>>(outAL, wamean, w_g1, we);
  k_bnstats<<<E1_, 256, 0, stream>>>(we, bn_g, bn_b, wcA, wcB);
  k_gemm2<<<150*30, 128, 0, stream>>>(we, wcA, wcB, wg2t, b_g2, w_g3, wapre);
  k_soft<<<B_, 256, 0, stream>>>(wapre, b_clf, wa, out);
  k_dnc<<<B_*11, 256, 0, stream>>>(outAL, wa, w_clf, out);
}